// Round 1
// baseline (5959.949 us; speedup 1.0000x reference)
//
#include <hip/hip_runtime.h>
#include <hip/hip_bf16.h>
#include <stdint.h>

// Leaky RNN: v_t = 0.9 v_{t-1} + 0.1 (W_hid fr_{t-1} + b_hid + u_t), fr = relu(v)
// Phase A: u_proj (fp32 tiled GEMM) written into d_out in place.
// Phase B: persistent 64-WG scan, W_hid slices bf16-stationary in LDS,
//          cross-WG fr exchange via global bf16 + monotonic agent-scope flags.

#define SEQ   1024
#define BATCH 64
#define INDIM 128
#define HID   512

typedef __attribute__((ext_vector_type(8))) short   short8;
typedef __attribute__((ext_vector_type(4))) float   floatx4;

__device__ __forceinline__ unsigned short f2bf(float x) {
  union { float f; unsigned int u; } v; v.f = x;
  unsigned int r = v.u + 0x7fffu + ((v.u >> 16) & 1u);  // RNE
  return (unsigned short)(r >> 16);
}

// ---------------- Phase A: u_proj = input @ W_in^T + b_in  (fp32) -----------
// Block: 256 threads, tile 64 sb-rows x 128 h-cols, K=128 split in 2 passes of 64.
#define TA_SB 64
#define TA_H  128
#define TA_K  64
#define APAD  65   // 64+1: odd dword stride breaks power-of-2 bank aliasing

__global__ __launch_bounds__(256) void uproj_kernel(
    const float* __restrict__ inp, const float* __restrict__ Win,
    const float* __restrict__ bin, float* __restrict__ out)
{
  __shared__ float sIn[TA_SB * APAD];   // 16.6 KB
  __shared__ float sW [TA_H  * APAD];   // 33.3 KB
  const int tid = threadIdx.x;
  const int sb0 = (blockIdx.x >> 2) * TA_SB;
  const int h0  = (blockIdx.x & 3) * TA_H;
  const int tx = tid & 15, ty = tid >> 4;

  float acc[4][8];
  #pragma unroll
  for (int i = 0; i < 4; ++i)
    #pragma unroll
    for (int j = 0; j < 8; ++j) acc[i][j] = 0.f;

  for (int kt = 0; kt < INDIM / TA_K; ++kt) {
    // stage input tile 64x64: 1024 float4 chunks, 4 per thread
    #pragma unroll
    for (int p = 0; p < 4; ++p) {
      int idx = tid + 256 * p;
      int row = idx >> 4, c4 = (idx & 15) << 2;
      const float4 v = *(const float4*)(inp + (size_t)(sb0 + row) * INDIM + kt * TA_K + c4);
      float* d = sIn + row * APAD + c4;
      d[0] = v.x; d[1] = v.y; d[2] = v.z; d[3] = v.w;
    }
    // stage W tile 128x64: 2048 float4 chunks, 8 per thread
    #pragma unroll
    for (int p = 0; p < 8; ++p) {
      int idx = tid + 256 * p;
      int row = idx >> 4, c4 = (idx & 15) << 2;
      const float4 v = *(const float4*)(Win + (size_t)(h0 + row) * INDIM + kt * TA_K + c4);
      float* d = sW + row * APAD + c4;
      d[0] = v.x; d[1] = v.y; d[2] = v.z; d[3] = v.w;
    }
    __syncthreads();

    for (int k = 0; k < TA_K; ++k) {
      float a[4], b[8];
      #pragma unroll
      for (int i = 0; i < 4; ++i) a[i] = sIn[(ty + 16 * i) * APAD + k];
      #pragma unroll
      for (int j = 0; j < 8; ++j) b[j] = sW[(tx + 16 * j) * APAD + k];
      #pragma unroll
      for (int i = 0; i < 4; ++i)
        #pragma unroll
        for (int j = 0; j < 8; ++j) acc[i][j] = fmaf(a[i], b[j], acc[i][j]);
    }
    __syncthreads();
  }

  #pragma unroll
  for (int j = 0; j < 8; ++j) {
    float bb = bin[h0 + tx + 16 * j];
    #pragma unroll
    for (int i = 0; i < 4; ++i)
      out[(size_t)(sb0 + ty + 16 * i) * HID + h0 + tx + 16 * j] = acc[i][j] + bb;
  }
}

// ---------------- Phase B: persistent sequential scan -----------------------
// 64 WGs = 4 batch-groups (M=16) x 16 hid-groups (N=32). 128 threads (2 waves),
// wave w owns n-tile [w*16, w*16+16). W_hid slice bf16 in LDS, rows padded to
// 520 (16B-aligned stride, 2-way-bank-only for b128 fragment reads).
#define HG   16
#define BGN  4
#define NPW  32
#define PADK 520

__global__ __launch_bounds__(128) void scan_kernel(
    const float* __restrict__ Whid, const float* __restrict__ bhid,
    float* __restrict__ uo,                 // d_out: u_proj in, fr out (in place)
    unsigned short* __restrict__ frbuf,     // [2][64][512] bf16 ping-pong
    int* __restrict__ flags)                // [4][16] monotonic step counters
{
  __shared__ unsigned short sW[NPW * PADK]; // 33.3 KB
  __shared__ unsigned short sA[16  * PADK]; // 16.6 KB

  const int tid  = threadIdx.x;
  const int lane = tid & 63;
  const int wave = tid >> 6;
  const int bg = blockIdx.x >> 4;
  const int hg = blockIdx.x & 15;
  const int b0 = bg * 16;
  const int h0 = hg * NPW;

  // Stage W_hid slice (rows h0..h0+31, fp32 -> bf16). 4096 float4-chunks/4.
  for (int idx = tid; idx < NPW * (HID / 4); idx += 128) {
    int row = idx >> 7, c4 = (idx & 127) << 2;
    const float4 wv = *(const float4*)(Whid + (size_t)(h0 + row) * HID + c4);
    unsigned short* d = sW + row * PADK + c4;
    d[0] = f2bf(wv.x); d[1] = f2bf(wv.y); d[2] = f2bf(wv.z); d[3] = f2bf(wv.w);
  }

  const int m16 = lane & 15;        // A-row / D-col position
  const int q   = lane >> 4;        // k-subchunk 0..3
  const int nl  = wave * 16 + m16;  // local n
  const int ng  = h0 + nl;          // global hid col
  const int mq  = q * 4;            // D-row base (C layout: row=(lane>>4)*4+reg)
  const float bias = bhid[ng];
  __syncthreads();

  const unsigned short* pA = sA + m16 * PADK + q * 8;
  const unsigned short* pW = sW + nl  * PADK + q * 8;

  float v[4] = {0.f, 0.f, 0.f, 0.f};
  const float OMA = 0.9f, AL = 0.1f;
  int* myflags = flags + bg * HG;

  for (int t = 0; t < SEQ; ++t) {
    // Prefetch u_t early: overlaps HBM latency with the flag wait.
    const float* up = uo + ((size_t)t * BATCH + b0 + mq) * HID + ng;
    float uu[4];
    #pragma unroll
    for (int r = 0; r < 4; ++r) uu[r] = up[(size_t)r * HID];

    floatx4 acc = {0.f, 0.f, 0.f, 0.f};
    if (t > 0) {
      if (tid < HG) {
        while (__hip_atomic_load(&myflags[tid], __ATOMIC_RELAXED,
                                 __HIP_MEMORY_SCOPE_AGENT) < t)
          __builtin_amdgcn_s_sleep(1);
      }
      __syncthreads();
      __builtin_amdgcn_fence(__ATOMIC_ACQUIRE, "agent");  // inv stale L1/L2

      // Stage fr[t-1] for my batch rows: 16x512 bf16, 16B chunks.
      const unsigned short* src = frbuf + (size_t)(((t - 1) & 1) * BATCH + b0) * HID;
      #pragma unroll
      for (int p = 0; p < 8; ++p) {
        int idx = tid + 128 * p;
        int row = idx >> 6, c8 = (idx & 63) << 3;
        *(short8*)(sA + row * PADK + c8) = *(const short8*)(src + row * HID + c8);
      }
      __syncthreads();

      #pragma unroll
      for (int kk = 0; kk < 16; ++kk) {
        short8 af = *(const short8*)(pA + kk * 32);
        short8 bf = *(const short8*)(pW + kk * 32);
        acc = __builtin_amdgcn_mfma_f32_16x16x32_bf16(af, bf, acc, 0, 0, 0);
      }
    }

    float fr[4];
    #pragma unroll
    for (int r = 0; r < 4; ++r) {
      v[r] = OMA * v[r] + AL * (acc[r] + bias + uu[r]);
      fr[r] = fmaxf(v[r], 0.f);
    }

    // Publish bf16 fr for consumers first (critical path), fp32 out after.
    unsigned short* fd = frbuf + (size_t)((t & 1) * BATCH + b0 + mq) * HID + ng;
    #pragma unroll
    for (int r = 0; r < 4; ++r) fd[(size_t)r * HID] = f2bf(fr[r]);

    __builtin_amdgcn_fence(__ATOMIC_RELEASE, "agent");  // drain + wb L2
    __syncthreads();
    if (tid == 0)
      __hip_atomic_store(&myflags[hg], t + 1, __ATOMIC_RELAXED,
                         __HIP_MEMORY_SCOPE_AGENT);

    float* od = uo + ((size_t)t * BATCH + b0 + mq) * HID + ng;
    #pragma unroll
    for (int r = 0; r < 4; ++r) od[(size_t)r * HID] = fr[r];
  }
}

// ---------------------------------------------------------------------------
extern "C" void kernel_launch(void* const* d_in, const int* in_sizes, int n_in,
                              void* d_out, int out_size, void* d_ws, size_t ws_size,
                              hipStream_t stream) {
  const float* inp  = (const float*)d_in[0];
  const float* Win  = (const float*)d_in[1];
  const float* bin  = (const float*)d_in[2];
  const float* Whid = (const float*)d_in[3];
  const float* bhid = (const float*)d_in[4];
  float* out = (float*)d_out;

  unsigned short* frbuf = (unsigned short*)d_ws;                 // 131072 B
  int* flags = (int*)((char*)d_ws + (size_t)2 * BATCH * HID * 2);

  hipMemsetAsync(flags, 0, BGN * HG * sizeof(int), stream);
  uproj_kernel<<<dim3((65536 / TA_SB) * (HID / TA_H)), dim3(256), 0, stream>>>(
      inp, Win, bin, out);
  scan_kernel<<<dim3(BGN * HG), dim3(128), 0, stream>>>(
      Whid, bhid, out, frbuf, flags);
}

// Round 2
// 3515.919 us; speedup vs baseline: 1.6951x; 1.6951x over previous
//
#include <hip/hip_runtime.h>
#include <hip/hip_bf16.h>
#include <stdint.h>

// Leaky RNN: v_t = 0.9 v_{t-1} + 0.1 (W_hid fr_{t-1} + b_hid + u_t), fr = relu(v)
// Phase A: u_proj (fp32 tiled GEMM) written into d_out in place.
// Phase B: persistent 64-WG scan. Cross-WG fr exchange via 64-bit relaxed
//   AGENT-scope atomics (bypass stale per-XCD L2, meet at Infinity Cache) --
//   NO buffer_wbl2/buffer_inv fences. fr is published in MFMA A-fragment
//   order so consumers load fragments IC->registers directly.

#define SEQ   1024
#define BATCH 64
#define INDIM 128
#define HID   512

typedef __attribute__((ext_vector_type(8))) short   short8;
typedef __attribute__((ext_vector_type(4))) float   floatx4;
typedef unsigned long long ull;

__device__ __forceinline__ unsigned short f2bf(float x) {
  union { float f; unsigned int u; } v; v.f = x;
  unsigned int r = v.u + 0x7fffu + ((v.u >> 16) & 1u);  // RNE
  return (unsigned short)(r >> 16);
}
__device__ __forceinline__ ull pack4(unsigned short a, unsigned short b,
                                     unsigned short c, unsigned short d) {
  return (ull)a | ((ull)b << 16) | ((ull)c << 32) | ((ull)d << 48);
}

// ---------------- Phase A: u_proj = input @ W_in^T + b_in  (fp32) -----------
#define TA_SB 64
#define TA_H  128
#define TA_K  64
#define APAD  65

__global__ __launch_bounds__(256) void uproj_kernel(
    const float* __restrict__ inp, const float* __restrict__ Win,
    const float* __restrict__ bin, float* __restrict__ out)
{
  __shared__ float sIn[TA_SB * APAD];
  __shared__ float sW [TA_H  * APAD];
  const int tid = threadIdx.x;
  const int sb0 = (blockIdx.x >> 2) * TA_SB;
  const int h0  = (blockIdx.x & 3) * TA_H;
  const int tx = tid & 15, ty = tid >> 4;

  float acc[4][8];
  #pragma unroll
  for (int i = 0; i < 4; ++i)
    #pragma unroll
    for (int j = 0; j < 8; ++j) acc[i][j] = 0.f;

  for (int kt = 0; kt < INDIM / TA_K; ++kt) {
    #pragma unroll
    for (int p = 0; p < 4; ++p) {
      int idx = tid + 256 * p;
      int row = idx >> 4, c4 = (idx & 15) << 2;
      const float4 v = *(const float4*)(inp + (size_t)(sb0 + row) * INDIM + kt * TA_K + c4);
      float* d = sIn + row * APAD + c4;
      d[0] = v.x; d[1] = v.y; d[2] = v.z; d[3] = v.w;
    }
    #pragma unroll
    for (int p = 0; p < 8; ++p) {
      int idx = tid + 256 * p;
      int row = idx >> 4, c4 = (idx & 15) << 2;
      const float4 v = *(const float4*)(Win + (size_t)(h0 + row) * INDIM + kt * TA_K + c4);
      float* d = sW + row * APAD + c4;
      d[0] = v.x; d[1] = v.y; d[2] = v.z; d[3] = v.w;
    }
    __syncthreads();

    for (int k = 0; k < TA_K; ++k) {
      float a[4], b[8];
      #pragma unroll
      for (int i = 0; i < 4; ++i) a[i] = sIn[(ty + 16 * i) * APAD + k];
      #pragma unroll
      for (int j = 0; j < 8; ++j) b[j] = sW[(tx + 16 * j) * APAD + k];
      #pragma unroll
      for (int i = 0; i < 4; ++i)
        #pragma unroll
        for (int j = 0; j < 8; ++j) acc[i][j] = fmaf(a[i], b[j], acc[i][j]);
    }
    __syncthreads();
  }

  #pragma unroll
  for (int j = 0; j < 8; ++j) {
    float bb = bin[h0 + tx + 16 * j];
    #pragma unroll
    for (int i = 0; i < 4; ++i)
      out[(size_t)(sb0 + ty + 16 * i) * HID + h0 + tx + 16 * j] = acc[i][j] + bb;
  }
}

// ---------------- Phase B: persistent sequential scan -----------------------
// 64 WGs = 4 batch-groups (M=16) x 16 hid-groups (N=32, i.e. k-chunk kk=hg).
// frA fragment buffer: [slot=2][bg=4][kk=16][lane=64][16B] = 128 KB.
#define HG   16
#define NPW  32
#define BGN  4
#define SXS  20   // sX row stride (ushorts): 8B-aligned b64 writes, spread banks

__global__ __launch_bounds__(128) void scan_kernel(
    const float* __restrict__ Whid, const float* __restrict__ bhid,
    float* __restrict__ uo,      // d_out: u_proj in, fr out (in place)
    ull* __restrict__ frA,       // fragment ping-pong, 2*4*16*64*2 ull
    int* __restrict__ flags)     // [4][16] monotonic step counters
{
  __shared__ unsigned short sWf[2 * HG * 64 * 8];  // 32 KB, fragment-ordered
  __shared__ unsigned short sX [NPW * SXS];        // 1.3 KB transpose buffer

  const int tid  = threadIdx.x;
  const int lane = tid & 63;
  const int wave = tid >> 6;
  const int bg = blockIdx.x >> 4;
  const int hg = blockIdx.x & 15;
  const int b0 = bg * 16;
  const int h0 = hg * NPW;

  // ---- Stage W_hid slice into LDS in B-fragment order (one-time) ----------
  // value at (w, kk, l, j) = bf16(W[h0 + w*16 + (l&15)][kk*32 + (l>>4)*8 + j])
  for (int idx = tid; idx < NPW * (HID / 4); idx += 128) {
    int row = idx >> 7, c4 = (idx & 127) << 2;           // row: n-local, c4: k
    const float4 wv = *(const float4*)(Whid + (size_t)(h0 + row) * HID + c4);
    int w = row >> 4, cn = row & 15;
    int kk = c4 >> 5, q = (c4 >> 3) & 3, j0 = c4 & 7;    // j0 in {0,4}
    ull pk = pack4(f2bf(wv.x), f2bf(wv.y), f2bf(wv.z), f2bf(wv.w));
    *(ull*)(sWf + (((w * HG + kk) * 64 + (q * 16 + cn)) * 8 + j0)) = pk;
  }

  const int cn = lane & 15;           // output col within 16 (D: col=lane&15)
  const int q  = lane >> 4;
  const int mq = q * 4;               // D rows mq..mq+3 (row=(lane>>4)*4+reg)
  const int nl = wave * 16 + cn;      // n-local in [0,32)
  const int ng = h0 + nl;             // global hid col
  const float bias = bhid[ng];

  // producer fragment-store mapping: thread -> (consumer-lane pl, half ph)
  const int pl  = tid >> 1, ph = tid & 1;
  const int pm  = pl & 15;                       // fragment m (batch row)
  const int pk0 = (pl >> 4) * 8 + ph * 4;        // k-local in [0,32)
  int* flg = flags + bg * HG;
  __syncthreads();

  float v[4] = {0.f, 0.f, 0.f, 0.f};
  const float OMA = 0.9f, AL = 0.1f;

  for (int t = 0; t < SEQ; ++t) {
    // Prefetch u_t early (plain cached loads; overlaps the flag wait).
    const float* up = uo + ((size_t)t * BATCH + b0 + mq) * HID + ng;
    float uu[4];
    #pragma unroll
    for (int r = 0; r < 4; ++r) uu[r] = up[(size_t)r * HID];

    floatx4 acc0 = {0.f, 0.f, 0.f, 0.f};
    floatx4 acc1 = {0.f, 0.f, 0.f, 0.f};
    if (t > 0) {
      if (tid < HG) {
        while (__hip_atomic_load(&flg[tid], __ATOMIC_RELAXED,
                                 __HIP_MEMORY_SCOPE_AGENT) < t) {}
      }
      __syncthreads();

      const int slot = (t - 1) & 1;
      const ull* ap = frA + (size_t)(slot * BGN + bg) * HG * 64 * 2;
      ull lo[HG], hi[HG];
      #pragma unroll
      for (int kk = 0; kk < HG; ++kk) {
        const ull* p = ap + ((size_t)kk * 64 + lane) * 2;
        lo[kk] = __hip_atomic_load(p,     __ATOMIC_RELAXED, __HIP_MEMORY_SCOPE_AGENT);
        hi[kk] = __hip_atomic_load(p + 1, __ATOMIC_RELAXED, __HIP_MEMORY_SCOPE_AGENT);
      }
      #pragma unroll
      for (int kk = 0; kk < HG; ++kk) {
        union { ull u[2]; short8 s; } af;
        af.u[0] = lo[kk]; af.u[1] = hi[kk];
        short8 bf = *(const short8*)(sWf + ((size_t)(wave * HG + kk) * 64 + lane) * 8);
        if (kk & 1) acc1 = __builtin_amdgcn_mfma_f32_16x16x32_bf16(af.s, bf, acc1, 0, 0, 0);
        else        acc0 = __builtin_amdgcn_mfma_f32_16x16x32_bf16(af.s, bf, acc0, 0, 0, 0);
      }
    }

    float fr[4];
    #pragma unroll
    for (int r = 0; r < 4; ++r) {
      v[r] = OMA * v[r] + AL * (acc0[r] + acc1[r] + bias + uu[r]);
      fr[r] = fmaxf(v[r], 0.f);
    }

    // ---- publish fr in A-fragment order (critical path) ----
    // 1) in-LDS transpose: sX[n-local][m], 4 contiguous m per thread (b64)
    *(ull*)(sX + nl * SXS + mq) = pack4(f2bf(fr[0]), f2bf(fr[1]),
                                        f2bf(fr[2]), f2bf(fr[3]));
    __syncthreads();
    // 2) gather 4 k-consecutive bf16 for (m=pm, k=pk0..pk0+3), one 8B atomic
    {
      unsigned short g0 = sX[(pk0 + 0) * SXS + pm];
      unsigned short g1 = sX[(pk0 + 1) * SXS + pm];
      unsigned short g2 = sX[(pk0 + 2) * SXS + pm];
      unsigned short g3 = sX[(pk0 + 3) * SXS + pm];
      const int slot = t & 1;
      ull* dst = frA + ((size_t)((slot * BGN + bg) * HG + hg) * 64 + pl) * 2 + ph;
      __hip_atomic_store(dst, pack4(g0, g1, g2, g3),
                         __ATOMIC_RELAXED, __HIP_MEMORY_SCOPE_AGENT);
    }
    // 3) order data -> flag: per-wave ack at coherence point, then WG-wide
    asm volatile("s_waitcnt vmcnt(0)" ::: "memory");
    __syncthreads();
    if (tid == 0)
      __hip_atomic_store(&flg[hg], t + 1, __ATOMIC_RELAXED,
                         __HIP_MEMORY_SCOPE_AGENT);

    // fp32 output (off critical path, plain cached stores)
    float* op = uo + ((size_t)t * BATCH + b0 + mq) * HID + ng;
    #pragma unroll
    for (int r = 0; r < 4; ++r) op[(size_t)r * HID] = fr[r];
  }
}

// ---------------------------------------------------------------------------
extern "C" void kernel_launch(void* const* d_in, const int* in_sizes, int n_in,
                              void* d_out, int out_size, void* d_ws, size_t ws_size,
                              hipStream_t stream) {
  const float* inp  = (const float*)d_in[0];
  const float* Win  = (const float*)d_in[1];
  const float* bin  = (const float*)d_in[2];
  const float* Whid = (const float*)d_in[3];
  const float* bhid = (const float*)d_in[4];
  float* out = (float*)d_out;

  ull* frA   = (ull*)d_ws;                              // 131072 B
  int* flags = (int*)((char*)d_ws + 131072);            // 256 B

  hipMemsetAsync(flags, 0, BGN * HG * sizeof(int), stream);
  uproj_kernel<<<dim3((65536 / TA_SB) * (HID / TA_H)), dim3(256), 0, stream>>>(
      inp, Win, bin, out);
  scan_kernel<<<dim3(BGN * HG), dim3(128), 0, stream>>>(
      Whid, bhid, out, frA, flags);
}

// Round 3
// 2413.651 us; speedup vs baseline: 2.4693x; 1.4567x over previous
//
#include <hip/hip_runtime.h>
#include <hip/hip_bf16.h>
#include <stdint.h>

// Leaky RNN: v_t = 0.9 v_{t-1} + 0.1 (W_hid fr_{t-1} + b_hid + u_t), fr = relu(v)
// Phase A: u_proj (fp32 tiled GEMM) written into d_out in place.
// Phase B: persistent 64-WG scan. Cross-WG fr exchange via relaxed agent-scope
//   8B atomics in MFMA A-fragment order. SELF-VALIDATING: fr>=0 so bf16 sign
//   bits are free -- producers OR a step-parity tag into all sign bits and
//   store fire-and-forget; consumers poll their own fragment loads until every
//   packet carries the expected tag (no flags, no vmcnt(0) ack, no fences).
//   ABA over the 4-step tag period is excluded by per-location coherence: the
//   consumer observed the opposite-tag value at these addresses 2 steps ago.

#define SEQ   1024
#define BATCH 64
#define INDIM 128
#define HID   512
#define HG    16   // hid groups (k-chunks of 32)
#define BGN   4    // batch groups of 16
#define SXS   20   // transpose-buffer row stride (ushorts)

typedef __attribute__((ext_vector_type(8))) short   short8;
typedef __attribute__((ext_vector_type(4))) float   floatx4;
typedef unsigned long long ull;

__device__ __forceinline__ unsigned short f2bf(float x) {
  union { float f; unsigned int u; } v; v.f = x;
  unsigned int r = v.u + 0x7fffu + ((v.u >> 16) & 1u);  // RNE
  return (unsigned short)(r >> 16);
}
__device__ __forceinline__ ull pack4(unsigned short a, unsigned short b,
                                     unsigned short c, unsigned short d) {
  return (ull)a | ((ull)b << 16) | ((ull)c << 32) | ((ull)d << 48);
}

// ---------------- Phase A: u_proj = input @ W_in^T + b_in  (fp32) -----------
#define TA_SB 64
#define TA_H  128
#define TA_K  64
#define APAD  65

__global__ __launch_bounds__(256) void uproj_kernel(
    const float* __restrict__ inp, const float* __restrict__ Win,
    const float* __restrict__ bin, float* __restrict__ out)
{
  __shared__ float sIn[TA_SB * APAD];
  __shared__ float sW [TA_H  * APAD];
  const int tid = threadIdx.x;
  const int sb0 = (blockIdx.x >> 2) * TA_SB;
  const int h0  = (blockIdx.x & 3) * TA_H;
  const int tx = tid & 15, ty = tid >> 4;

  float acc[4][8];
  #pragma unroll
  for (int i = 0; i < 4; ++i)
    #pragma unroll
    for (int j = 0; j < 8; ++j) acc[i][j] = 0.f;

  for (int kt = 0; kt < INDIM / TA_K; ++kt) {
    #pragma unroll
    for (int p = 0; p < 4; ++p) {
      int idx = tid + 256 * p;
      int row = idx >> 4, c4 = (idx & 15) << 2;
      const float4 v = *(const float4*)(inp + (size_t)(sb0 + row) * INDIM + kt * TA_K + c4);
      float* d = sIn + row * APAD + c4;
      d[0] = v.x; d[1] = v.y; d[2] = v.z; d[3] = v.w;
    }
    #pragma unroll
    for (int p = 0; p < 8; ++p) {
      int idx = tid + 256 * p;
      int row = idx >> 4, c4 = (idx & 15) << 2;
      const float4 v = *(const float4*)(Win + (size_t)(h0 + row) * INDIM + kt * TA_K + c4);
      float* d = sW + row * APAD + c4;
      d[0] = v.x; d[1] = v.y; d[2] = v.z; d[3] = v.w;
    }
    __syncthreads();

    for (int k = 0; k < TA_K; ++k) {
      float a[4], b[8];
      #pragma unroll
      for (int i = 0; i < 4; ++i) a[i] = sIn[(ty + 16 * i) * APAD + k];
      #pragma unroll
      for (int j = 0; j < 8; ++j) b[j] = sW[(tx + 16 * j) * APAD + k];
      #pragma unroll
      for (int i = 0; i < 4; ++i)
        #pragma unroll
        for (int j = 0; j < 8; ++j) acc[i][j] = fmaf(a[i], b[j], acc[i][j]);
    }
    __syncthreads();
  }

  #pragma unroll
  for (int j = 0; j < 8; ++j) {
    float bb = bin[h0 + tx + 16 * j];
    #pragma unroll
    for (int i = 0; i < 4; ++i)
      out[(size_t)(sb0 + ty + 16 * i) * HID + h0 + tx + 16 * j] = acc[i][j] + bb;
  }
}

// ---------------- Phase B: persistent sequential scan -----------------------
// 64 WGs = 4 bg (M=16) x 16 hg (N=32 = k-chunk kk=hg).
// frA: [slot=2][bg=4][kk=16][lane=64][2 ull] = 128 KB.
__global__ __launch_bounds__(128) void scan_kernel(
    const float* __restrict__ Whid, const float* __restrict__ bhid,
    float* __restrict__ uo,      // d_out: u_proj in, fr out (in place)
    ull* __restrict__ frA)
{
  __shared__ unsigned short sX[32 * SXS];   // 1.3 KB transpose buffer

  const int tid  = threadIdx.x;
  const int lane = tid & 63;
  const int wave = tid >> 6;
  const int bg = blockIdx.x >> 4;
  const int hg = blockIdx.x & 15;
  const int b0 = bg * 16;
  const int h0 = hg * 32;

  const int cn = lane & 15;          // D: col within 16 / B: n within 16
  const int q  = lane >> 4;
  const int mq = q * 4;              // D rows mq..mq+3
  const int nl = wave * 16 + cn;     // n-local in [0,32)
  const int ng = h0 + nl;            // global hid col
  const float bias = bhid[ng];

  // ---- one-time: W_hid B-fragments straight into registers (bf16) ---------
  // bw[kk] lane layout: B[n=lane&15][k=(lane>>4)*8+j], row = ng.
  short8 bw[HG];
  {
    const float* wrow = Whid + (size_t)ng * HID + q * 8;
    #pragma unroll
    for (int kk = 0; kk < HG; ++kk) {
      const float4 a = *(const float4*)(wrow + kk * 32);
      const float4 b = *(const float4*)(wrow + kk * 32 + 4);
      union { unsigned short s[8]; short8 v; } u;
      u.s[0] = f2bf(a.x); u.s[1] = f2bf(a.y); u.s[2] = f2bf(a.z); u.s[3] = f2bf(a.w);
      u.s[4] = f2bf(b.x); u.s[5] = f2bf(b.y); u.s[6] = f2bf(b.z); u.s[7] = f2bf(b.w);
      bw[kk] = u.v;
    }
  }

  // producer fragment-store mapping: thread -> (consumer-lane pl, half ph)
  const int pl  = tid >> 1, ph = tid & 1;
  const int pm  = pl & 15;                   // fragment m (batch row)
  const int pk0 = (pl >> 4) * 8 + ph * 4;    // k-local base in [0,32)

  const ull MASKT = 0x8000800080008000ull;
  float v[4] = {0.f, 0.f, 0.f, 0.f};
  const float OMA = 0.9f, AL = 0.1f;

  for (int t = 0; t < SEQ; ++t) {
    // Prefetch u_t (plain cached loads; completes while we poll).
    const float* up = uo + ((size_t)t * BATCH + b0 + mq) * HID + ng;
    float uu[4];
    #pragma unroll
    for (int r = 0; r < 4; ++r) uu[r] = up[(size_t)r * HID];

    floatx4 acc[4];
    #pragma unroll
    for (int j = 0; j < 4; ++j) acc[j] = (floatx4){0.f, 0.f, 0.f, 0.f};

    if (t > 0) {
      const int slot = (t - 1) & 1;
      const ull expv = (((t - 1) >> 1) & 1) ? MASKT : 0ull;
      const ull* ap = frA + (size_t)(slot * BGN + bg) * HG * 128 + (size_t)lane * 2;
      ull lo[HG], hi[HG];
      for (;;) {
        int ok = 1;
        #pragma unroll
        for (int kk = 0; kk < HG; ++kk) {
          lo[kk] = __hip_atomic_load(ap + (size_t)kk * 128,
                                     __ATOMIC_RELAXED, __HIP_MEMORY_SCOPE_AGENT);
          hi[kk] = __hip_atomic_load(ap + (size_t)kk * 128 + 1,
                                     __ATOMIC_RELAXED, __HIP_MEMORY_SCOPE_AGENT);
          ok &= (int)(((lo[kk] & MASKT) == expv) & ((hi[kk] & MASKT) == expv));
        }
        if (__all(ok)) break;
      }
      #pragma unroll
      for (int kk = 0; kk < HG; ++kk) {
        union { ull u[2]; short8 s; } af;
        af.u[0] = lo[kk] & ~MASKT;
        af.u[1] = hi[kk] & ~MASKT;
        acc[kk & 3] = __builtin_amdgcn_mfma_f32_16x16x32_bf16(af.s, bw[kk],
                                                              acc[kk & 3], 0, 0, 0);
      }
    }

    float fr[4];
    #pragma unroll
    for (int r = 0; r < 4; ++r) {
      float s = acc[0][r] + acc[1][r] + acc[2][r] + acc[3][r];
      v[r] = OMA * v[r] + AL * (s + bias + uu[r]);
      fr[r] = fmaxf(v[r], 0.f);
    }

    // ---- publish fr_t in A-fragment order, tagged, fire-and-forget ----
    *(ull*)(sX + nl * SXS + mq) = pack4(f2bf(fr[0]), f2bf(fr[1]),
                                        f2bf(fr[2]), f2bf(fr[3]));
    __syncthreads();
    {
      unsigned short g0 = sX[(pk0 + 0) * SXS + pm];
      unsigned short g1 = sX[(pk0 + 1) * SXS + pm];
      unsigned short g2 = sX[(pk0 + 2) * SXS + pm];
      unsigned short g3 = sX[(pk0 + 3) * SXS + pm];
      ull pk = pack4(g0, g1, g2, g3);
      if ((t >> 1) & 1) pk |= MASKT;          // step-parity tag in sign bits
      ull* dst = frA + (size_t)(((t & 1) * BGN + bg) * HG + hg) * 128
                     + (size_t)pl * 2 + ph;
      __hip_atomic_store(dst, pk, __ATOMIC_RELAXED, __HIP_MEMORY_SCOPE_AGENT);
    }

    // fp32 output (off critical path)
    float* op = uo + ((size_t)t * BATCH + b0 + mq) * HID + ng;
    #pragma unroll
    for (int r = 0; r < 4; ++r) op[(size_t)r * HID] = fr[r];

    __syncthreads();   // protect sX against next iteration's overwrite
  }
}

// ---------------------------------------------------------------------------
extern "C" void kernel_launch(void* const* d_in, const int* in_sizes, int n_in,
                              void* d_out, int out_size, void* d_ws, size_t ws_size,
                              hipStream_t stream) {
  const float* inp  = (const float*)d_in[0];
  const float* Win  = (const float*)d_in[1];
  const float* bin  = (const float*)d_in[2];
  const float* Whid = (const float*)d_in[3];
  const float* bhid = (const float*)d_in[4];
  float* out = (float*)d_out;

  ull* frA = (ull*)d_ws;   // 128 KB; 0xAA poison reads as tag=1 => invalid early

  uproj_kernel<<<dim3((65536 / TA_SB) * (HID / TA_H)), dim3(256), 0, stream>>>(
      inp, Win, bin, out);
  scan_kernel<<<dim3(BGN * HG), dim3(128), 0, stream>>>(
      Whid, bhid, out, frA);
}